// Round 3
// baseline (423.708 us; speedup 1.0000x reference)
//
#include <hip/hip_runtime.h>

// ---------------------------------------------------------------------------
// VoxelTripletLoss — Round 3: NS=32 (4 blocks/CU), coalesced W reads,
// coalesced prep stores. B=64, M=2048, FEAT=512, N=32768.
//
//   K1 prep:     V -> (v_hi, v_lo) bf16 frag-permuted (1KB-contig wave
//                stores), exact v_sq[b], 1/||anchor||, 1/||key||
//   K2 gemm_big: dotp[ns][b][m] via mfma_f32_32x32x16_bf16 (vhi*w + vlo*w),
//                wsqp[ns][m] from f32 W during staging. NS=32 k-splits.
//   K3 keydist:  keyp[b][m] = anchor.keys^T + wsq reduce
//   K4 rowpart:  per (b, m-slice) hardest pos/neg partials
//   K5 final:    combine -> masked mean -> d_out[0]
// ---------------------------------------------------------------------------

typedef __attribute__((ext_vector_type(8)))  short bf16x8;
typedef __attribute__((ext_vector_type(16))) float f32x16;

constexpr int   Mdim   = 2048;
constexpr int   Nvox   = 32768;
constexpr int   NS     = 32;        // k-splits for big GEMM
constexpr float BETA   = 0.8333333f;
constexpr float MARGIN = 0.2f;
constexpr float BIGV   = 1.0e9f;

// workspace layout (float offsets); total ~26 MB
constexpr size_t OFF_VSQ  = 0;                        // 64
constexpr size_t OFF_AINV = 64;                       // 64
constexpr size_t OFF_KINV = 128;                      // 2048
constexpr size_t OFF_WSQ  = 2176;                     // 2048
constexpr size_t OFF_WSQP = 4224;                     // NS*2048 = 65536
constexpr size_t OFF_PHP  = 69760;                    // 256
constexpr size_t OFF_PHN  = 70016;                    // 256
constexpr size_t OFF_PAP  = 70272;                    // 256
constexpr size_t OFF_PAN  = 70528;                    // 256
constexpr size_t OFF_KEYP = 70784;                    // 64*2048 = 131072
constexpr size_t OFF_DOTP = 201856;                   // NS*64*2048 = 4194304
constexpr size_t OFF_VHI  = 4396160;                  // 2M ushort = 1048576 floats
constexpr size_t OFF_VLO  = 5444736;                  // 1048576 floats

__device__ __forceinline__ unsigned int bf16rne(float x) {
    unsigned int u = __float_as_uint(x);
    return (u + 0x7FFFu + ((u >> 16) & 1u)) >> 16;
}
__device__ __forceinline__ int pk2(unsigned int lo, unsigned int hi) {
    return (int)(lo | (hi << 16));
}
__device__ __forceinline__ void async16(const ushort* g, ushort* l) {
    __builtin_amdgcn_global_load_lds(
        (const __attribute__((address_space(1))) unsigned int*)g,
        (__attribute__((address_space(3))) unsigned int*)l, 16, 0, 0);
}

// ---------------------------------------------------------------------------
// K1 prep.
// Blocks [0,512): V convert. unit uid = blk*8 + wave*2 + u covers
//   (c = uid>>3, s = (uid>>1)&3, bh = uid&1): lane l handles row
//   b = bh*32 + (l&31), 8 floats at col c*64 + s*16 + (l>>5)*8.
//   Global read: 32 full 64B lines / instr. Store: lane*16B -> 1KB contig.
//   frag layout (ushort idx): (k>>6)*4096 + (b>>5)*2048 + ((k>>4)&3)*512
//     + ((b&31) + 32*((k>>3)&1))*8 + (k&7)
// Blocks [512,576): exact v_sq[b].
// Blocks [576,1104): feature-row norms (4 rows per block).
// ---------------------------------------------------------------------------
__global__ __launch_bounds__(256) void prep_kernel(
    const float* __restrict__ vox, const float* __restrict__ anc,
    const float* __restrict__ keys,
    ushort* __restrict__ vhi, ushort* __restrict__ vlo,
    float* __restrict__ vsq, float* __restrict__ ainv, float* __restrict__ kinv)
{
    const int tid = threadIdx.x;
    const int lane = tid & 63;
    const int wave = tid >> 6;
    if (blockIdx.x < 512) {
        #pragma unroll
        for (int u = 0; u < 2; ++u) {
            const int uid = blockIdx.x * 8 + wave * 2 + u;
            const int bh = uid & 1, s = (uid >> 1) & 3, c = uid >> 3;
            const int b   = bh * 32 + (lane & 31);
            const int col = c * 64 + s * 16 + (lane >> 5) * 8;
            const float4* src = reinterpret_cast<const float4*>(vox + (size_t)b * Nvox + col);
            const float4 x0 = src[0], x1 = src[1];
            const float e[8] = {x0.x, x0.y, x0.z, x0.w, x1.x, x1.y, x1.z, x1.w};
            unsigned int h[8], l8[8];
            #pragma unroll
            for (int q = 0; q < 8; ++q) {
                const unsigned int hb = bf16rne(e[q]);
                h[q] = hb;
                l8[q] = bf16rne(e[q] - __uint_as_float(hb << 16));
            }
            const int4 hp = { pk2(h[0],h[1]), pk2(h[2],h[3]), pk2(h[4],h[5]), pk2(h[6],h[7]) };
            const int4 lp = { pk2(l8[0],l8[1]), pk2(l8[2],l8[3]), pk2(l8[4],l8[5]), pk2(l8[6],l8[7]) };
            const size_t base = (size_t)c * 4096 + bh * 2048 + s * 512 + lane * 8;
            *reinterpret_cast<int4*>(vhi + base) = hp;
            *reinterpret_cast<int4*>(vlo + base) = lp;
        }
    } else if (blockIdx.x < 576) {
        const int b = blockIdx.x - 512;
        const float4* src = reinterpret_cast<const float4*>(vox + (size_t)b * Nvox);
        float p = 0.f;
        for (int i = tid; i < Nvox / 4; i += 256) {
            const float4 x = src[i];
            p = fmaf(x.x, x.x, p); p = fmaf(x.y, x.y, p);
            p = fmaf(x.z, x.z, p); p = fmaf(x.w, x.w, p);
        }
        #pragma unroll
        for (int off = 32; off > 0; off >>= 1) p += __shfl_down(p, off);
        __shared__ float sb[4];
        if (lane == 0) sb[wave] = p;
        __syncthreads();
        if (tid == 0) vsq[b] = sb[0] + sb[1] + sb[2] + sb[3];
    } else {
        const int r = (blockIdx.x - 576) * 4 + wave;     // 0..2111
        const float* src = (r < 64) ? (anc + (size_t)r * 512)
                                    : (keys + (size_t)(r - 64) * 512);
        const float4* s4 = reinterpret_cast<const float4*>(src);
        const float4 x = s4[lane];
        const float4 y = s4[lane + 64];
        float p = 0.f;
        p = fmaf(x.x, x.x, p); p = fmaf(x.y, x.y, p);
        p = fmaf(x.z, x.z, p); p = fmaf(x.w, x.w, p);
        p = fmaf(y.x, y.x, p); p = fmaf(y.y, y.y, p);
        p = fmaf(y.z, y.z, p); p = fmaf(y.w, y.w, p);
        #pragma unroll
        for (int off = 32; off > 0; off >>= 1) p += __shfl_down(p, off);
        if (lane == 0) {
            const float inv = 1.f / fmaxf(sqrtf(p), 1e-8f);
            if (r < 64) ainv[r] = inv; else kinv[r - 64] = inv;
        }
    }
}

// ---------------------------------------------------------------------------
// K2: dotp[ns][64][2048] via MFMA. 1024 blocks = 32 mb x 32 ns (4/CU).
// Per 64-k chunk: V hi/lo via global_load_lds (frag order), W f32 register-
// prefetched with full-line coalescing (col = ch*64 + j*16 + sq*4),
// converted to bf16, ds_write_b64 x4 in frag order. 8 k-steps, 2 MFMA each.
// ---------------------------------------------------------------------------
__global__ __launch_bounds__(256, 4) void gemm_big(
    const ushort* __restrict__ vhi, const ushort* __restrict__ vlo,
    const float* __restrict__ W,
    float* __restrict__ dotp, float* __restrict__ wsqp)
{
    __shared__ ushort sVhi[4096], sVlo[4096], sW[4096];   // 8 KB each
    __shared__ float red[256];

    const int tid  = threadIdx.x;
    const int lane = tid & 63;
    const int wave = tid >> 6;
    const int mb   = blockIdx.x & 31;       // m-block
    const int ns   = blockIdx.x >> 5;       // k-split (1024 k each)
    const int srow = tid >> 2;              // staged W row 0..63
    const int sq   = tid & 3;

    const float*  wptr = W + (size_t)(mb * 64 + srow) * Nvox + ns * 1024 + sq * 4;
    const ushort* vhig = vhi + (size_t)(ns * 16) * 4096 + wave * 1024 + lane * 8;
    const ushort* vlog = vlo + (size_t)(ns * 16) * 4096 + wave * 1024 + lane * 8;
    ushort* ldsVhi = &sVhi[wave * 1024];    // wave-uniform DMA dest
    ushort* ldsVlo = &sVlo[wave * 1024];

    const int wr = wave >> 1, wc = wave & 1;
    f32x16 acc = {};
    float wsq = 0.f;

    float4 wreg[4];
    #pragma unroll
    for (int j = 0; j < 4; ++j) wreg[j] = *reinterpret_cast<const float4*>(wptr + j * 16);

    // thread's 4 els in s-block j: pos = (srow&31 + 32*(sq>>1))*8 + (sq&1)*4
    const int woffbase = (srow >> 5) * 2048 + ((srow & 31) + 32 * (sq >> 1)) * 8 + (sq & 1) * 4;

    for (int ch = 0; ch < 16; ++ch) {
        int2 pj[4];
        #pragma unroll
        for (int j = 0; j < 4; ++j) {
            const float e[4] = {wreg[j].x, wreg[j].y, wreg[j].z, wreg[j].w};
            unsigned int hb[4];
            #pragma unroll
            for (int q = 0; q < 4; ++q) {
                wsq = fmaf(e[q], e[q], wsq);
                hb[q] = bf16rne(e[q]);
            }
            pj[j] = (int2){ pk2(hb[0], hb[1]), pk2(hb[2], hb[3]) };
        }
        __syncthreads();                     // all waves done reading prev chunk
        async16(vhig + (size_t)ch * 4096,       ldsVhi);
        async16(vhig + (size_t)ch * 4096 + 512, ldsVhi + 512);
        async16(vlog + (size_t)ch * 4096,       ldsVlo);
        async16(vlog + (size_t)ch * 4096 + 512, ldsVlo + 512);
        #pragma unroll
        for (int j = 0; j < 4; ++j)
            *reinterpret_cast<int2*>(&sW[woffbase + j * 512]) = pj[j];
        if (ch < 15) {
            #pragma unroll
            for (int j = 0; j < 4; ++j)
                wreg[j] = *reinterpret_cast<const float4*>(wptr + (ch + 1) * 64 + j * 16);
        }
        __syncthreads();                     // V DMA + W writes visible
        #pragma unroll
        for (int s = 0; s < 4; ++s) {
            const bf16x8 ah = *reinterpret_cast<const bf16x8*>(&sVhi[wr * 2048 + s * 512 + lane * 8]);
            const bf16x8 al = *reinterpret_cast<const bf16x8*>(&sVlo[wr * 2048 + s * 512 + lane * 8]);
            const bf16x8 bh = *reinterpret_cast<const bf16x8*>(&sW[wc * 2048 + s * 512 + lane * 8]);
            acc = __builtin_amdgcn_mfma_f32_32x32x16_bf16(ah, bh, acc, 0, 0, 0);
            acc = __builtin_amdgcn_mfma_f32_32x32x16_bf16(al, bh, acc, 0, 0, 0);
        }
    }

    // epilogue: C layout col=lane&31, row=(reg&3)+8*(reg>>2)+4*(lane>>5)
    const int col   = lane & 31;
    const int rbase = 4 * (lane >> 5);
    const size_t out_m = (size_t)(mb * 64 + wc * 32 + col);
    #pragma unroll
    for (int r = 0; r < 16; ++r) {
        const int row = (r & 3) + 8 * (r >> 2) + rbase;
        const int b   = wr * 32 + row;
        dotp[(size_t)(ns * 64 + b) * Mdim + out_m] = acc[r];
    }
    red[tid] = wsq;
    __syncthreads();
    if (tid < 64)
        wsqp[(size_t)ns * Mdim + mb * 64 + tid] =
            red[tid*4] + red[tid*4+1] + red[tid*4+2] + red[tid*4+3];
}

// ---------------------------------------------------------------------------
// K3: blocks [0,256): key dots (8 m-rows per block, keys staged in LDS);
//     blocks [256,264): wsq[m] = sum_s wsqp[s][m]
// ---------------------------------------------------------------------------
__global__ __launch_bounds__(256) void keydist_kernel(
    const float* __restrict__ anc, const float* __restrict__ keys,
    const float* __restrict__ wsqp, float* __restrict__ keyp,
    float* __restrict__ wsq)
{
    const int tid = threadIdx.x;
    if (blockIdx.x >= 256) {
        const int m = (blockIdx.x - 256) * 256 + tid;
        float s = 0.f;
        #pragma unroll
        for (int sp = 0; sp < NS; ++sp) s += wsqp[(size_t)sp * Mdim + m];
        wsq[m] = s;
        return;
    }
    __shared__ float kk[8 * 516];
    const int mt = blockIdx.x * 8;
    {
        const int row = tid >> 5, colb = (tid & 31) * 16;
        const float4* src = reinterpret_cast<const float4*>(keys + (size_t)(mt + row) * 512 + colb);
        #pragma unroll
        for (int j = 0; j < 4; ++j)
            *reinterpret_cast<float4*>(&kk[row * 516 + colb + j * 4]) = src[j];
    }
    __syncthreads();
    const int b = tid >> 2, msub = tid & 3;
    const float* arow = anc + (size_t)b * 512;
    const float* k0 = &kk[msub * 516];
    const float* k1 = &kk[(msub + 4) * 516];
    float d0 = 0.f, d1 = 0.f;
    for (int k = 0; k < 512; k += 4) {
        const float4 a = *reinterpret_cast<const float4*>(arow + k);
        const float4 x = *reinterpret_cast<const float4*>(k0 + k);
        const float4 y = *reinterpret_cast<const float4*>(k1 + k);
        d0 = fmaf(a.x, x.x, d0); d0 = fmaf(a.y, x.y, d0);
        d0 = fmaf(a.z, x.z, d0); d0 = fmaf(a.w, x.w, d0);
        d1 = fmaf(a.x, y.x, d1); d1 = fmaf(a.y, y.y, d1);
        d1 = fmaf(a.z, y.z, d1); d1 = fmaf(a.w, y.w, d1);
    }
    keyp[(size_t)b * Mdim + mt + msub]     = d0;
    keyp[(size_t)b * Mdim + mt + msub + 4] = d1;
}

// ---------------------------------------------------------------------------
// K4: grid 256 = 64 b x 4 m-slices (512 m each): partial hardest pos/neg
// ---------------------------------------------------------------------------
__global__ __launch_bounds__(256) void rowpart_kernel(
    const float* __restrict__ dotp, const float* __restrict__ wsq,
    const float* __restrict__ keyp, const float* __restrict__ vsq,
    const float* __restrict__ ainv, const float* __restrict__ kinv,
    float* __restrict__ php, float* __restrict__ phn,
    float* __restrict__ pap, float* __restrict__ pan)
{
    const int bid = blockIdx.x, tid = threadIdx.x;
    const int b = bid >> 2, sl = bid & 3;
    const float vs = vsq[b];
    const float ai = ainv[b];
    float hp = -BIGV, hn = BIGV, ap = 0.f, an = 0.f;
    #pragma unroll
    for (int rep = 0; rep < 2; ++rep) {
        const int m = sl * 512 + rep * 256 + tid;
        float dot = 0.f;
        #pragma unroll
        for (int s = 0; s < NS; ++s) dot += dotp[(size_t)(s * 64 + b) * Mdim + m];
        const float sv = 1.f - (vs + wsq[m] - 2.f * dot) * (1.f / 32768.f);
        const float kd = 1.f - keyp[(size_t)b * Mdim + m] * ai * kinv[m];
        if (sv > BETA) { ap = 1.f; hp = fmaxf(hp, kd); }
        if (sv < BETA) { an = 1.f; hn = fminf(hn, kd); }
    }
    #pragma unroll
    for (int off = 32; off > 0; off >>= 1) {
        hp = fmaxf(hp, __shfl_down(hp, off));
        hn = fminf(hn, __shfl_down(hn, off));
        ap = fmaxf(ap, __shfl_down(ap, off));
        an = fmaxf(an, __shfl_down(an, off));
    }
    __shared__ float sb[16];
    const int wv = tid >> 6;
    if ((tid & 63) == 0) {
        sb[wv * 4 + 0] = hp; sb[wv * 4 + 1] = hn;
        sb[wv * 4 + 2] = ap; sb[wv * 4 + 3] = an;
    }
    __syncthreads();
    if (tid == 0) {
        for (int w2 = 1; w2 < 4; ++w2) {
            hp = fmaxf(hp, sb[w2 * 4 + 0]);
            hn = fminf(hn, sb[w2 * 4 + 1]);
            ap = fmaxf(ap, sb[w2 * 4 + 2]);
            an = fmaxf(an, sb[w2 * 4 + 3]);
        }
        php[bid] = hp; phn[bid] = hn; pap[bid] = ap; pan[bid] = an;
    }
}

// ---------------------------------------------------------------------------
// K5: single block: combine 4 partials per b -> loss/valid -> masked mean
// ---------------------------------------------------------------------------
__global__ void final_kernel(const float* __restrict__ php, const float* __restrict__ phn,
                             const float* __restrict__ pap, const float* __restrict__ pan,
                             float* __restrict__ out)
{
    const int t = threadIdx.x;   // 256
    float hp = php[t], hn = phn[t], ap = pap[t], an = pan[t];
    hp = fmaxf(hp, __shfl_down(hp, 2)); hp = fmaxf(hp, __shfl_down(hp, 1));
    hn = fminf(hn, __shfl_down(hn, 2)); hn = fminf(hn, __shfl_down(hn, 1));
    ap = fmaxf(ap, __shfl_down(ap, 2)); ap = fmaxf(ap, __shfl_down(ap, 1));
    an = fmaxf(an, __shfl_down(an, 2)); an = fmaxf(an, __shfl_down(an, 1));
    __shared__ float sl[64], sc[64];
    if ((t & 3) == 0) {
        const int b = t >> 2;
        const float valid = (ap > 0.f && an > 0.f) ? 1.f : 0.f;
        sl[b] = fmaxf(hp - hn + MARGIN, 0.f) * valid;
        sc[b] = valid;
    }
    __syncthreads();
    if (t < 64) {
        float l = sl[t], c = sc[t];
        #pragma unroll
        for (int off = 32; off > 0; off >>= 1) {
            l += __shfl_down(l, off);
            c += __shfl_down(c, off);
        }
        if (t == 0) out[0] = (c > 0.f) ? (l / c) : 0.f;
    }
}

// ---------------------------------------------------------------------------
extern "C" void kernel_launch(void* const* d_in, const int* in_sizes, int n_in,
                              void* d_out, int out_size, void* d_ws, size_t ws_size,
                              hipStream_t stream) {
    const float* anchor = (const float*)d_in[0];   // (64, 512)
    const float* voxels = (const float*)d_in[1];   // (64, 32768)
    const float* keys   = (const float*)d_in[2];   // (2048, 512)
    const float* vals   = (const float*)d_in[3];   // (2048, 32768)

    float* ws = (float*)d_ws;
    float*  vsq  = ws + OFF_VSQ;
    float*  ainv = ws + OFF_AINV;
    float*  kinv = ws + OFF_KINV;
    float*  wsq  = ws + OFF_WSQ;
    float*  wsqp = ws + OFF_WSQP;
    float*  php  = ws + OFF_PHP;
    float*  phn  = ws + OFF_PHN;
    float*  pap  = ws + OFF_PAP;
    float*  pan  = ws + OFF_PAN;
    float*  keyp = ws + OFF_KEYP;
    float*  dotp = ws + OFF_DOTP;
    ushort* vhi  = (ushort*)(ws + OFF_VHI);
    ushort* vlo  = (ushort*)(ws + OFF_VLO);

    prep_kernel<<<1104, 256, 0, stream>>>(voxels, anchor, keys, vhi, vlo, vsq, ainv, kinv);
    gemm_big<<<32 * NS, 256, 0, stream>>>(vhi, vlo, vals, dotp, wsqp);
    keydist_kernel<<<264, 256, 0, stream>>>(anchor, keys, wsqp, keyp, wsq);
    rowpart_kernel<<<256, 256, 0, stream>>>(dotp, wsq, keyp, vsq, ainv, kinv,
                                            php, phn, pap, pan);
    final_kernel<<<1, 256, 0, stream>>>(php, phn, pap, pan, (float*)d_out);
}